// Round 6
// baseline (40.329 us; speedup 1.0000x reference)
//
#include <hip/hip_runtime.h>

#define DIM 1024
#define HEADS 16
#define BATCH 2
#define SEQ 2048

// ws float layout (all final vectors, written by K1, read by K2):
#define WS_QA 0            // qa[1024] = w_in @ wq
#define WS_QB 1024         // qb[1024] = b_in @ wq
#define WS_KA 2048         // ka[1024] = w_in @ wk
#define WS_VA 3072         // va[1024] = w_in @ wv
#define WS_VB 4096         // vb[1024] = b_in @ wv
#define WS_U  5120         // u[1024]  = wo @ wf

// grid 320: [0,192) QKV d-slice blocks (mat m = b/64, d-range of 16);
//           [192,320) wo@wf row blocks (8 rows each, 2 per wave)
__global__ __launch_bounds__(256) void k1_weights(
        const float* __restrict__ w_in, const float* __restrict__ b_in,
        const float* __restrict__ wq,   const float* __restrict__ wk,
        const float* __restrict__ wv,   const float* __restrict__ wo,
        const float* __restrict__ wf,   float* __restrict__ ws) {
    const int bid = blockIdx.x;
    const int tid = threadIdx.x;
    if (bid < 192) {
        const int m  = bid >> 6;          // 0=wq 1=wk 2=wv
        const int d0 = (bid & 63) * 16;
        const int dl = tid & 15, jg = tid >> 4;   // 16 d-lanes x 16 j-groups
        const float* Wm = (m == 0) ? wq : (m == 1) ? wk : wv;
        const int j0 = jg * 64;
        float a1 = 0.f, a2 = 0.f;
        #pragma unroll 8
        for (int j = j0; j < j0 + 64; ++j) {
            const float w = Wm[j * DIM + d0 + dl];
            a1 += w_in[j] * w;
            if (m != 1) a2 += b_in[j] * w;
        }
        __shared__ float s1[16][17], s2[16][17];
        s1[jg][dl] = a1;
        if (m != 1) s2[jg][dl] = a2;
        __syncthreads();
        if (tid < 16) {
            float f1 = 0.f, f2 = 0.f;
            #pragma unroll
            for (int g = 0; g < 16; ++g) {
                f1 += s1[g][tid];
                if (m != 1) f2 += s2[g][tid];
            }
            const int d = d0 + tid;
            if (m == 0)      { ws[WS_QA + d] = f1; ws[WS_QB + d] = f2; }
            else if (m == 1) { ws[WS_KA + d] = f1; }
            else             { ws[WS_VA + d] = f1; ws[WS_VB + d] = f2; }
        }
    } else {
        const int wave = tid >> 6, lane = tid & 63;
        const int rb = bid - 192;
        #pragma unroll
        for (int rr = 0; rr < 2; ++rr) {
            const int row = rb * 8 + wave * 2 + rr;
            const float4* wo4 = reinterpret_cast<const float4*>(wo + row * DIM);
            const float4* wf4 = reinterpret_cast<const float4*>(wf);
            float s = 0.f;
            #pragma unroll
            for (int e = lane; e < 256; e += 64) {
                const float4 av = wo4[e], bv = wf4[e];
                s += av.x * bv.x + av.y * bv.y + av.z * bv.z + av.w * bv.w;
            }
            #pragma unroll
            for (int off = 32; off; off >>= 1) s += __shfl_down(s, off);
            if (lane == 0) ws[WS_U + row] = s;
        }
    }
}

// 512 blocks x 256 threads; block p handles q in {p, 1023-p, 1024+p, 2047-p} x 2 batches.
// Each block recomputes the 49 scalars from the L2-hot vectors (no combine kernel).
__global__ __launch_bounds__(256) void k2_attn(
        const float* __restrict__ x,  const float* __restrict__ bo,
        const float* __restrict__ wf, const float* __restrict__ bf,
        const float* __restrict__ ws, float* __restrict__ out) {
    const int p = blockIdx.x;
    const int tid = threadIdx.x;
    const int wave = tid >> 6, lane = tid & 63;

    __shared__ float xs[BATCH * SEQ];   // 16 KB
    __shared__ float sA[HEADS], sC[HEADS], sG[HEADS];
    __shared__ float c0p[4];
    __shared__ float wpart[8][4];

    // stage both x rows (16 KB, L1/L2-hot)
    {
        const float4* x4 = reinterpret_cast<const float4*>(x);
        float4* xs4 = reinterpret_cast<float4*>(xs);
        #pragma unroll
        for (int t = tid; t < (BATCH * SEQ) / 4; t += 256) xs4[t] = x4[t];
    }

    // per-head scalars: wave w owns heads 4w..4w+3; lane l <-> d = h*64+l
    #pragma unroll
    for (int hh = 0; hh < 4; ++hh) {
        const int h = wave * 4 + hh;
        const int d = h * 64 + lane;
        const float qa = ws[WS_QA + d], qb = ws[WS_QB + d], ka = ws[WS_KA + d];
        const float va = ws[WS_VA + d], u  = ws[WS_U + d];
        float pA = qa * ka, pC = qb * ka, pG = va * u;
        #pragma unroll
        for (int off = 32; off; off >>= 1) {
            pA += __shfl_down(pA, off);
            pC += __shfl_down(pC, off);
            pG += __shfl_down(pG, off);
        }
        if (lane == 0) { sA[h] = pA; sC[h] = pC; sG[h] = pG; }
    }
    // c0 partials: wave w sums d in [w*256, w*256+256)
    {
        float s = 0.f;
        #pragma unroll
        for (int t = 0; t < 4; ++t) {
            const int d = wave * 256 + t * 64 + lane;
            s += ws[WS_VB + d] * ws[WS_U + d] + bo[d] * wf[d];
        }
        #pragma unroll
        for (int off = 32; off; off >>= 1) s += __shfl_down(s, off);
        if (lane == 0) c0p[wave] = s;
    }
    __syncthreads();

    const float c0 = c0p[0] + c0p[1] + c0p[2] + c0p[3] + bf[0];
    const int h0 = wave * 4;
    const float A0 = sA[h0 + 0], C0 = sC[h0 + 0], G0 = sG[h0 + 0];
    const float A1 = sA[h0 + 1], C1 = sC[h0 + 1], G1 = sG[h0 + 1];
    const float A2 = sA[h0 + 2], C2 = sC[h0 + 2], G2 = sG[h0 + 2];
    const float A3 = sA[h0 + 3], C3 = sC[h0 + 3], G3 = sG[h0 + 3];

    for (int t8 = 0; t8 < 8; ++t8) {
        const int bb  = t8 >> 2;
        const int sel = t8 & 3;
        const int q = (sel == 0) ? p : (sel == 1) ? 1023 - p : (sel == 2) ? 1024 + p : 2047 - p;
        const float* xrow = xs + bb * SEQ;
        const float xq = xrow[q];
        // logits are alpha*x_k (additive consts cancel in softmax); |alpha*x| << 88
        const float a0 = 0.125f * (A0 * xq + C0);
        const float a1 = 0.125f * (A1 * xq + C1);
        const float a2 = 0.125f * (A2 * xq + C2);
        const float a3 = 0.125f * (A3 * xq + C3);
        float n0 = 0.f, n1 = 0.f, n2 = 0.f, n3 = 0.f;
        float d0 = 0.f, d1 = 0.f, d2 = 0.f, d3 = 0.f;
        for (int k = lane; k <= q; k += 64) {
            const float xk = xrow[k];
            const float e0 = __expf(a0 * xk);
            const float e1 = __expf(a1 * xk);
            const float e2 = __expf(a2 * xk);
            const float e3 = __expf(a3 * xk);
            d0 += e0; n0 += e0 * xk;
            d1 += e1; n1 += e1 * xk;
            d2 += e2; n2 += e2 * xk;
            d3 += e3; n3 += e3 * xk;
        }
        #pragma unroll
        for (int off = 32; off; off >>= 1) {
            n0 += __shfl_down(n0, off); d0 += __shfl_down(d0, off);
            n1 += __shfl_down(n1, off); d1 += __shfl_down(d1, off);
            n2 += __shfl_down(n2, off); d2 += __shfl_down(d2, off);
            n3 += __shfl_down(n3, off); d3 += __shfl_down(d3, off);
        }
        if (lane == 0)
            wpart[t8][wave] = G0 * (n0 / d0) + G1 * (n1 / d1) + G2 * (n2 / d2) + G3 * (n3 / d3);
    }
    __syncthreads();
    if (tid < 8) {
        const int bb  = tid >> 2;
        const int sel = tid & 3;
        const int q = (sel == 0) ? p : (sel == 1) ? 1023 - p : (sel == 2) ? 1024 + p : 2047 - p;
        out[bb * SEQ + q] = c0 + wpart[tid][0] + wpart[tid][1] + wpart[tid][2] + wpart[tid][3];
    }
}

extern "C" void kernel_launch(void* const* d_in, const int* in_sizes, int n_in,
                              void* d_out, int out_size, void* d_ws, size_t ws_size,
                              hipStream_t stream) {
    const float* x    = (const float*)d_in[0];
    const float* w_in = (const float*)d_in[1];
    const float* b_in = (const float*)d_in[2];
    const float* wq   = (const float*)d_in[3];
    const float* wk   = (const float*)d_in[4];
    const float* wv   = (const float*)d_in[5];
    const float* wo   = (const float*)d_in[6];
    const float* bo   = (const float*)d_in[7];
    const float* wf   = (const float*)d_in[8];
    const float* bf   = (const float*)d_in[9];
    float* out = (float*)d_out;
    float* ws  = (float*)d_ws;

    k1_weights<<<320, 256, 0, stream>>>(w_in, b_in, wq, wk, wv, wo, wf, ws);
    k2_attn<<<512, 256, 0, stream>>>(x, bo, wf, bf, ws, out);
}

// Round 7
// 19.612 us; speedup vs baseline: 2.0564x; 2.0564x over previous
//
#include <hip/hip_runtime.h>

#define DIM 1024
#define HEADS 16
#define BATCH 2
#define SEQ 2048
#define NCHUNK 64
#define NTERM 32           // Taylor coefficients T_0..T_31

// ws float layout:
#define WS_U    5120       // u[1024] = wo @ wf
#define WS_A    6144       // A[16]
#define WS_C    6160       // C[16]
#define WS_G    6176       // G[16]
#define WS_C0H  6192       // c0 head-partials [16]
#define WS_PART 8192       // P[c][w][1024], c<64, w in {qa,qb,ka,va,vb}
#define WS_T    344064     // T[b][n][k]: prefix sums of x^n/n!, 2*32*2048 floats

// grid 384: [0,64) QKV chunk blocks (float4, 16 rows each);
//           [64,320) wo@wf row blocks (one wave per row);
//           [320,384) prefix-scan blocks, one per (batch, n)
__global__ __launch_bounds__(256) void k1_weights(
        const float* __restrict__ x,
        const float* __restrict__ w_in, const float* __restrict__ b_in,
        const float* __restrict__ wq,   const float* __restrict__ wk,
        const float* __restrict__ wv,   const float* __restrict__ wo,
        const float* __restrict__ wf,   float* __restrict__ ws) {
    const int bid = blockIdx.x;
    const int tid = threadIdx.x;
    if (bid < NCHUNK) {
        const int j0 = bid * 16;
        float4 qa = {0,0,0,0}, qb = {0,0,0,0}, ka = {0,0,0,0};
        float4 va = {0,0,0,0}, vb = {0,0,0,0};
        #pragma unroll
        for (int j = j0; j < j0 + 16; ++j) {
            const float wi = w_in[j], bi = b_in[j];
            const float4 cq = ((const float4*)(wq + j * DIM))[tid];
            const float4 ck = ((const float4*)(wk + j * DIM))[tid];
            const float4 cv = ((const float4*)(wv + j * DIM))[tid];
            qa.x += wi * cq.x; qa.y += wi * cq.y; qa.z += wi * cq.z; qa.w += wi * cq.w;
            qb.x += bi * cq.x; qb.y += bi * cq.y; qb.z += bi * cq.z; qb.w += bi * cq.w;
            ka.x += wi * ck.x; ka.y += wi * ck.y; ka.z += wi * ck.z; ka.w += wi * ck.w;
            va.x += wi * cv.x; va.y += wi * cv.y; va.z += wi * cv.z; va.w += wi * cv.w;
            vb.x += bi * cv.x; vb.y += bi * cv.y; vb.z += bi * cv.z; vb.w += bi * cv.w;
        }
        float4* base = (float4*)(ws + WS_PART + bid * 5 * DIM);
        base[tid]           = qa;
        base[256 + tid]     = qb;
        base[2 * 256 + tid] = ka;
        base[3 * 256 + tid] = va;
        base[4 * 256 + tid] = vb;
    } else if (bid < 320) {
        const int wave = tid >> 6, lane = tid & 63;
        const int row = (bid - NCHUNK) * 4 + wave;
        const float4* wo4 = (const float4*)(wo + row * DIM);
        const float4* wf4 = (const float4*)wf;
        float s = 0.f;
        #pragma unroll
        for (int e = lane; e < 256; e += 64) {
            const float4 a = wo4[e], b = wf4[e];
            s += a.x * b.x + a.y * b.y + a.z * b.z + a.w * b.w;
        }
        #pragma unroll
        for (int off = 32; off; off >>= 1) s += __shfl_down(s, off);
        if (lane == 0) ws[WS_U + row] = s;
    } else {
        // prefix scan of x^n/n! for one (b, n); 256 threads x 8 elements
        const int sb = bid - 320;
        const int b = sb >> 5, n = sb & 31;
        const float* xb = x + b * SEQ;
        const float4 xa = ((const float4*)xb)[2 * tid];
        const float4 xc = ((const float4*)xb)[2 * tid + 1];
        float xv[8] = {xa.x, xa.y, xa.z, xa.w, xc.x, xc.y, xc.z, xc.w};
        float pw[8];
        #pragma unroll
        for (int e = 0; e < 8; ++e) pw[e] = 1.f;
        float f = 1.f;
        for (int i = 1; i <= n; ++i) {          // runtime n <= 31
            f *= (float)i;
            #pragma unroll
            for (int e = 0; e < 8; ++e) pw[e] *= xv[e];
        }
        const float rf = 1.0f / f;
        float p[8];
        float s = 0.f;
        #pragma unroll
        for (int e = 0; e < 8; ++e) { s += pw[e] * rf; p[e] = s; }
        // wave-inclusive scan of per-thread sums
        const int lane = tid & 63, wv = tid >> 6;
        float incl = s;
        #pragma unroll
        for (int off = 1; off < 64; off <<= 1) {
            const float v = __shfl_up(incl, off);
            if (lane >= off) incl += v;
        }
        __shared__ float wsum[4];
        if (lane == 63) wsum[wv] = incl;
        __syncthreads();
        float base = incl - s;                  // exclusive within wave
        if (wv > 0) base += wsum[0];
        if (wv > 1) base += wsum[1];
        if (wv > 2) base += wsum[2];
        float* Trow = ws + WS_T + (b * NTERM + n) * SEQ;
        ((float4*)Trow)[2 * tid]     = make_float4(base + p[0], base + p[1], base + p[2], base + p[3]);
        ((float4*)Trow)[2 * tid + 1] = make_float4(base + p[4], base + p[5], base + p[6], base + p[7]);
    }
}

// 16 blocks (one per head) x 256 threads
__global__ __launch_bounds__(256) void k2_combine(
        const float* __restrict__ bo, const float* __restrict__ wf,
        const float* __restrict__ bf, float* __restrict__ ws) {
    const int h = blockIdx.x;
    const int tid = threadIdx.x;
    const int c4 = tid >> 6, dl = tid & 63;
    const int d = h * 64 + dl;
    float qa = 0.f, qb = 0.f, ka = 0.f, va = 0.f, vb = 0.f;
    for (int c = c4; c < NCHUNK; c += 4) {
        const float* base = ws + WS_PART + c * 5 * DIM + d;
        qa += base[0];
        qb += base[DIM];
        ka += base[2 * DIM];
        va += base[3 * DIM];
        vb += base[4 * DIM];
    }
    __shared__ float red5[4][5][64];
    red5[c4][0][dl] = qa;
    red5[c4][1][dl] = qb;
    red5[c4][2][dl] = ka;
    red5[c4][3][dl] = va;
    red5[c4][4][dl] = vb;
    __syncthreads();
    if (tid < 64) {
        const float fqa = red5[0][0][tid] + red5[1][0][tid] + red5[2][0][tid] + red5[3][0][tid];
        const float fqb = red5[0][1][tid] + red5[1][1][tid] + red5[2][1][tid] + red5[3][1][tid];
        const float fka = red5[0][2][tid] + red5[1][2][tid] + red5[2][2][tid] + red5[3][2][tid];
        const float fva = red5[0][3][tid] + red5[1][3][tid] + red5[2][3][tid] + red5[3][3][tid];
        const float fvb = red5[0][4][tid] + red5[1][4][tid] + red5[2][4][tid] + red5[3][4][tid];
        const int dd = h * 64 + tid;
        const float u = ws[WS_U + dd];
        float pA = fqa * fka;
        float pC = fqb * fka;
        float pG = fva * u;
        float pc = fvb * u + bo[dd] * wf[dd];
        #pragma unroll
        for (int off = 32; off; off >>= 1) {
            pA += __shfl_down(pA, off);
            pC += __shfl_down(pC, off);
            pG += __shfl_down(pG, off);
            pc += __shfl_down(pc, off);
        }
        if (tid == 0) {
            ws[WS_A + h]   = pA;
            ws[WS_C + h]   = pC;
            ws[WS_G + h]   = pG;
            ws[WS_C0H + h] = pc + (h == 0 ? bf[0] : 0.f);
        }
    }
}

// 256 blocks x 256 threads: thread = (b, q, h); Horner eval of num/den in alpha.
// den = sum_n alpha^n T_n(q),  num = sum_n alpha^n (n+1) T_{n+1}(q)
__global__ __launch_bounds__(256) void k3_eval(
        const float* __restrict__ x, const float* __restrict__ ws,
        float* __restrict__ out) {
    const int g = blockIdx.x * 256 + threadIdx.x;    // 65536 = 2*2048*16
    const int h = g & 15;
    const int q = (g >> 4) & (SEQ - 1);
    const int b = g >> 15;
    const float xq = x[b * SEQ + q];
    const float al = 0.125f * (ws[WS_A + h] * xq + ws[WS_C + h]);
    const float* T = ws + WS_T + b * NTERM * SEQ + q;
    float tr[NTERM];
    #pragma unroll
    for (int n = 0; n < NTERM; ++n) tr[n] = T[n * SEQ];
    float den = tr[31];
    float num = 31.f * tr[31];
    #pragma unroll
    for (int j = 30; j >= 1; --j) {
        den = den * al + tr[j];
        num = num * al + (float)j * tr[j];
    }
    den = den * al + tr[0];                          // T_0 = q+1
    float r = ws[WS_G + h] * (num / den);
    r += __shfl_down(r, 8);
    r += __shfl_down(r, 4);
    r += __shfl_down(r, 2);
    r += __shfl_down(r, 1);
    if (h == 0) {
        float c0 = 0.f;
        #pragma unroll
        for (int i = 0; i < HEADS; ++i) c0 += ws[WS_C0H + i];
        out[b * SEQ + q] = c0 + r;
    }
}

extern "C" void kernel_launch(void* const* d_in, const int* in_sizes, int n_in,
                              void* d_out, int out_size, void* d_ws, size_t ws_size,
                              hipStream_t stream) {
    const float* x    = (const float*)d_in[0];
    const float* w_in = (const float*)d_in[1];
    const float* b_in = (const float*)d_in[2];
    const float* wq   = (const float*)d_in[3];
    const float* wk   = (const float*)d_in[4];
    const float* wv   = (const float*)d_in[5];
    const float* wo   = (const float*)d_in[6];
    const float* bo   = (const float*)d_in[7];
    const float* wf   = (const float*)d_in[8];
    const float* bf   = (const float*)d_in[9];
    float* out = (float*)d_out;
    float* ws  = (float*)d_ws;

    k1_weights<<<384, 256, 0, stream>>>(x, w_in, b_in, wq, wk, wv, wo, wf, ws);
    k2_combine<<<HEADS, 256, 0, stream>>>(bo, wf, bf, ws);
    k3_eval<<<256, 256, 0, stream>>>(x, ws, out);
}

// Round 8
// 16.150 us; speedup vs baseline: 2.4971x; 1.2143x over previous
//
#include <hip/hip_runtime.h>

#define DIM 1024
#define HEADS 16
#define BATCH 2
#define SEQ 2048
#define NTERM 32           // Taylor coefficients T_0..T_31

// ws float layout:
// Two partial sets over j-halves; each set: {qa,qb,ka,va,vb}[1024]
#define WS_P0   0
#define WS_P1   5120
#define WS_U    10240      // u[1024] = wo @ wf
#define WS_T    16384      // T[b][n][k]: prefix sums of x^n/n!, 2*32*2048 floats

// grid 320: [0,192)   QKV half-partials: m = bid/64, slice s = (bid&63)>>1, j-half = bid&1
//           [192,256) wo@wf rows, 16 per block
//           [256,320) prefix-scan blocks, one per (batch, n)
__global__ __launch_bounds__(256) void k1_weights(
        const float* __restrict__ x,
        const float* __restrict__ w_in, const float* __restrict__ b_in,
        const float* __restrict__ wq,   const float* __restrict__ wk,
        const float* __restrict__ wv,   const float* __restrict__ wo,
        const float* __restrict__ wf,   float* __restrict__ ws) {
    const int bid = blockIdx.x;
    const int tid = threadIdx.x;
    if (bid < 192) {
        const int m  = bid >> 6;               // 0=wq 1=wk 2=wv
        const int r  = bid & 63;
        const int jh = r & 1;                  // j-half
        const int d0 = (r >> 1) * 32;          // 32-wide d-slice
        const int dl = tid & 7;                // float4 col within slice
        const int jg = tid >> 3;               // 32 j-groups of 16 rows
        const int j0 = jh * 512 + jg * 16;
        const float* Wm = (m == 0) ? wq : (m == 1) ? wk : wv;
        float4 a1 = {0, 0, 0, 0}, a2 = {0, 0, 0, 0};
        #pragma unroll
        for (int i = 0; i < 16; ++i) {
            const int j = j0 + i;
            const float4 v = *reinterpret_cast<const float4*>(Wm + j * DIM + d0 + 4 * dl);
            const float wi = w_in[j];
            a1.x += wi * v.x; a1.y += wi * v.y; a1.z += wi * v.z; a1.w += wi * v.w;
            if (m != 1) {
                const float bi = b_in[j];
                a2.x += bi * v.x; a2.y += bi * v.y; a2.z += bi * v.z; a2.w += bi * v.w;
            }
        }
        __shared__ float sh1[32][33], sh2[32][33];
        sh1[jg][4 * dl + 0] = a1.x;
        sh1[jg][4 * dl + 1] = a1.y;
        sh1[jg][4 * dl + 2] = a1.z;
        sh1[jg][4 * dl + 3] = a1.w;
        if (m != 1) {
            sh2[jg][4 * dl + 0] = a2.x;
            sh2[jg][4 * dl + 1] = a2.y;
            sh2[jg][4 * dl + 2] = a2.z;
            sh2[jg][4 * dl + 3] = a2.w;
        }
        __syncthreads();
        if (tid < 32) {
            float f1 = 0.f, f2 = 0.f;
            #pragma unroll
            for (int g = 0; g < 32; ++g) {
                f1 += sh1[g][tid];
                if (m != 1) f2 += sh2[g][tid];
            }
            const int base = jh ? WS_P1 : WS_P0;
            const int d = d0 + tid;
            if (m == 0)      { ws[base + d] = f1; ws[base + 1024 + d] = f2; }
            else if (m == 1) { ws[base + 2048 + d] = f1; }
            else             { ws[base + 3072 + d] = f1; ws[base + 4096 + d] = f2; }
        }
    } else if (bid < 256) {
        // u[row] = wo[row,:] . wf ; 16 rows per block, 4 per wave
        const int wave = tid >> 6, lane = tid & 63;
        const int rb = bid - 192;
        #pragma unroll
        for (int rr = 0; rr < 4; ++rr) {
            const int row = rb * 16 + wave * 4 + rr;
            const float4* wo4 = reinterpret_cast<const float4*>(wo + row * DIM);
            const float4* wf4 = reinterpret_cast<const float4*>(wf);
            float s = 0.f;
            #pragma unroll
            for (int e = lane; e < 256; e += 64) {
                const float4 a = wo4[e], b = wf4[e];
                s += a.x * b.x + a.y * b.y + a.z * b.z + a.w * b.w;
            }
            #pragma unroll
            for (int off = 32; off; off >>= 1) s += __shfl_down(s, off);
            if (lane == 0) ws[WS_U + row] = s;
        }
    } else {
        // prefix scan of x^n/n! for one (b, n); 256 threads x 8 elements
        const int sb = bid - 256;
        const int b = sb >> 5, n = sb & 31;
        const float* xb = x + b * SEQ;
        const float4 xa = ((const float4*)xb)[2 * tid];
        const float4 xc = ((const float4*)xb)[2 * tid + 1];
        float xv[8] = {xa.x, xa.y, xa.z, xa.w, xc.x, xc.y, xc.z, xc.w};
        float pw[8];
        #pragma unroll
        for (int e = 0; e < 8; ++e) pw[e] = 1.f;
        float f = 1.f;
        for (int i = 1; i <= n; ++i) {          // runtime n <= 31
            f *= (float)i;
            #pragma unroll
            for (int e = 0; e < 8; ++e) pw[e] *= xv[e];
        }
        const float rf = 1.0f / f;
        float p[8];
        float s = 0.f;
        #pragma unroll
        for (int e = 0; e < 8; ++e) { s += pw[e] * rf; p[e] = s; }
        const int lane = tid & 63, wv = tid >> 6;
        float incl = s;
        #pragma unroll
        for (int off = 1; off < 64; off <<= 1) {
            const float v = __shfl_up(incl, off);
            if (lane >= off) incl += v;
        }
        __shared__ float wsum[4];
        if (lane == 63) wsum[wv] = incl;
        __syncthreads();
        float base = incl - s;                  // exclusive within wave
        if (wv > 0) base += wsum[0];
        if (wv > 1) base += wsum[1];
        if (wv > 2) base += wsum[2];
        float* Trow = ws + WS_T + (b * NTERM + n) * SEQ;
        ((float4*)Trow)[2 * tid]     = make_float4(base + p[0], base + p[1], base + p[2], base + p[3]);
        ((float4*)Trow)[2 * tid + 1] = make_float4(base + p[4], base + p[5], base + p[6], base + p[7]);
    }
}

// 256 blocks x 256 threads. Each block recomputes the 49 head scalars from the
// L2-hot partial vectors (~11 KB), then Horner-evaluates num/den per (b,q,h):
// den = sum_n alpha^n T_n(q),  num = sum_n alpha^n (n+1) T_{n+1}(q)
__global__ __launch_bounds__(256) void k2_eval(
        const float* __restrict__ x,  const float* __restrict__ bo,
        const float* __restrict__ wf, const float* __restrict__ bf,
        const float* __restrict__ ws, float* __restrict__ out) {
    const int tid = threadIdx.x;
    const int wave = tid >> 6, lane = tid & 63;

    __shared__ float sA[HEADS], sC[HEADS], sG[HEADS];
    __shared__ float c0p[4];

    #pragma unroll
    for (int hh = 0; hh < 4; ++hh) {
        const int h = wave * 4 + hh;
        const int d = h * 64 + lane;
        const float qa = ws[WS_P0 + d]        + ws[WS_P1 + d];
        const float qb = ws[WS_P0 + 1024 + d] + ws[WS_P1 + 1024 + d];
        const float ka = ws[WS_P0 + 2048 + d] + ws[WS_P1 + 2048 + d];
        const float va = ws[WS_P0 + 3072 + d] + ws[WS_P1 + 3072 + d];
        const float u  = ws[WS_U + d];
        float pA = qa * ka, pC = qb * ka, pG = va * u;
        #pragma unroll
        for (int off = 32; off; off >>= 1) {
            pA += __shfl_down(pA, off);
            pC += __shfl_down(pC, off);
            pG += __shfl_down(pG, off);
        }
        if (lane == 0) { sA[h] = pA; sC[h] = pC; sG[h] = pG; }
    }
    {
        float s = 0.f;
        #pragma unroll
        for (int t = 0; t < 4; ++t) {
            const int d = wave * 256 + t * 64 + lane;
            const float vb = ws[WS_P0 + 4096 + d] + ws[WS_P1 + 4096 + d];
            s += vb * ws[WS_U + d] + bo[d] * wf[d];
        }
        #pragma unroll
        for (int off = 32; off; off >>= 1) s += __shfl_down(s, off);
        if (lane == 0) c0p[wave] = s;
    }
    __syncthreads();
    const float c0 = c0p[0] + c0p[1] + c0p[2] + c0p[3] + bf[0];

    const int g = blockIdx.x * 256 + tid;    // 65536 = 2*2048*16
    const int h = g & 15;
    const int q = (g >> 4) & (SEQ - 1);
    const int b = g >> 15;
    const float xq = x[b * SEQ + q];
    const float al = 0.125f * (sA[h] * xq + sC[h]);
    const float* T = ws + WS_T + b * NTERM * SEQ + q;
    float tr[NTERM];
    #pragma unroll
    for (int n = 0; n < NTERM; ++n) tr[n] = T[n * SEQ];
    float den = tr[31];
    float num = 31.f * tr[31];
    #pragma unroll
    for (int j = 30; j >= 1; --j) {
        den = den * al + tr[j];
        num = num * al + (float)j * tr[j];
    }
    den = den * al + tr[0];                  // T_0 = q+1
    float r = sG[h] * (num / den);
    r += __shfl_down(r, 8);
    r += __shfl_down(r, 4);
    r += __shfl_down(r, 2);
    r += __shfl_down(r, 1);
    if (h == 0) out[b * SEQ + q] = c0 + r;
}

extern "C" void kernel_launch(void* const* d_in, const int* in_sizes, int n_in,
                              void* d_out, int out_size, void* d_ws, size_t ws_size,
                              hipStream_t stream) {
    const float* x    = (const float*)d_in[0];
    const float* w_in = (const float*)d_in[1];
    const float* b_in = (const float*)d_in[2];
    const float* wq   = (const float*)d_in[3];
    const float* wk   = (const float*)d_in[4];
    const float* wv   = (const float*)d_in[5];
    const float* wo   = (const float*)d_in[6];
    const float* bo   = (const float*)d_in[7];
    const float* wf   = (const float*)d_in[8];
    const float* bf   = (const float*)d_in[9];
    float* out = (float*)d_out;
    float* ws  = (float*)d_ws;

    k1_weights<<<320, 256, 0, stream>>>(x, w_in, b_in, wq, wk, wv, wo, wf, ws);
    k2_eval<<<256, 256, 0, stream>>>(x, bo, wf, bf, ws, out);
}